// Round 1
// 155.847 us; speedup vs baseline: 1.0816x; 1.0816x over previous
//
#include <hip/hip_runtime.h>
#include <stdint.h>

#define SC 192      // coarse samples (128 + 64)
#define SF 128      // fine (importance) samples
#define NT 128      // threads per block = 2 waves

// LDS weight-image offsets (floats)
#define WD1   0     // 96  (3x32 row-major)
#define BD1   96    // 32
#define WD2   128   // 32
#define BD2   160   // 1
#define BC2   161   // 3
#define NV4   164   // 32 x float4: (bc1[n], Wc1[32][n], Wc1[33][n], Wc1[34][n])
#define W24   292   // 32 x float4: (Wc2[n][0],[1],[2], 0)
#define SWTOT 420   // floats (105 float4s)

#define WS_FRAG_OFF 2048    // byte offset of Wc1 fp16 A-frags in d_ws
#define WS_NEED     4096

#define HSTRIDE 40  // ushort stride for H rows (80 B rows -> bank-friendly)
#define RGBS 4

using half8 = __attribute__((ext_vector_type(8))) _Float16;
using f32x4 = __attribute__((ext_vector_type(4))) float;

__device__ __forceinline__ float zlog_c(int t) {
  return (t < 128) ? (-1.0f + (float)t * 0.0078125f)
                   : ((float)(t - 128) * 0.015625f);
}
__device__ __forceinline__ float delta_c(int t) {
  if (t >= SC - 1) return 0.0f;
  return zlog_c(t + 1) - zlog_c(t);
}

__device__ __forceinline__ float fast_rcp(float x) { return __builtin_amdgcn_rcpf(x); }
__device__ __forceinline__ float fast_rsq(float x) { return __builtin_amdgcn_rsqf(x); }
__device__ __forceinline__ float exp10_f(float x) { return __expf(x * 2.30258509299f); }
__device__ __forceinline__ float softplus_f(float x) {
  return fmaxf(x, 0.0f) + __logf(1.0f + __expf(-fabsf(x)));
}

// fp16 helpers: pk2h = 1 HW instr (v_cvt_pkrtz_f16_f32); f2h = RTN scalar convert
__device__ __forceinline__ uint32_t pk2h(float a, float b) {
  auto p = __builtin_amdgcn_cvt_pkrtz(a, b);
  uint32_t u; __builtin_memcpy(&u, &p, 4); return u;
}
__device__ __forceinline__ unsigned short f2h(float f) {
  _Float16 h = (_Float16)f;
  unsigned short us; __builtin_memcpy(&us, &h, 2); return us;
}

__device__ __forceinline__ float4 ldsf4(const float* p) { return *(const float4*)p; }

// ---- DPP cross-lane (VALU pipe, no LDS): gfx9 row_shr / row_bcast sequence ----
template <int CTRL, int RMASK, int BMASK>
__device__ __forceinline__ float dpp_mov(float x, float oldv) {
  return __int_as_float(__builtin_amdgcn_update_dpp(
      __float_as_int(oldv), __float_as_int(x), CTRL, RMASK, BMASK, false));
}
// wave64 inclusive scans (LLVM AMDGPUAtomicOptimizer buildScan sequence)
__device__ __forceinline__ float dpp_scan_add(float v) {
  v += dpp_mov<0x111, 0xf, 0xf>(v, 0.0f);   // row_shr:1
  v += dpp_mov<0x112, 0xf, 0xf>(v, 0.0f);   // row_shr:2
  v += dpp_mov<0x114, 0xf, 0xf>(v, 0.0f);   // row_shr:4
  v += dpp_mov<0x118, 0xf, 0xf>(v, 0.0f);   // row_shr:8
  v += dpp_mov<0x142, 0xa, 0xf>(v, 0.0f);   // row_bcast:15 -> rows 1,3
  v += dpp_mov<0x143, 0xc, 0xf>(v, 0.0f);   // row_bcast:31 -> rows 2,3
  return v;
}
__device__ __forceinline__ float dpp_scan_mul(float v) {
  v *= dpp_mov<0x111, 0xf, 0xf>(v, 1.0f);
  v *= dpp_mov<0x112, 0xf, 0xf>(v, 1.0f);
  v *= dpp_mov<0x114, 0xf, 0xf>(v, 1.0f);
  v *= dpp_mov<0x118, 0xf, 0xf>(v, 1.0f);
  v *= dpp_mov<0x142, 0xa, 0xf>(v, 1.0f);
  v *= dpp_mov<0x143, 0xc, 0xf>(v, 1.0f);
  return v;
}

// JAX threefry2x32 with key = (0, 42)
__device__ __forceinline__ void threefry2x32_k42(uint32_t& x0, uint32_t& x1) {
  const uint32_t ks0 = 0u, ks1 = 42u;
  const uint32_t ks2 = ks0 ^ ks1 ^ 0x1BD11BDAu;
  const uint32_t ks[3] = {ks0, ks1, ks2};
  const int rot[2][4] = {{13, 15, 26, 6}, {17, 29, 16, 24}};
  x0 += ks[0];
  x1 += ks[1];
#pragma unroll
  for (int i = 0; i < 5; ++i) {
#pragma unroll
    for (int j = 0; j < 4; ++j) {
      x0 += x1;
      const int r = rot[i & 1][j];
      x1 = (x1 << r) | (x1 >> (32 - r));
      x1 ^= x0;
    }
    x0 += ks[(i + 1) % 3];
    x1 += ks[(i + 2) % 3] + (uint32_t)(i + 1);
  }
}

// ---- pre-pack kernel: weight image + fp16 Wc1 A-frags (identical for all blocks) ----
__global__ __launch_bounds__(NT) void pack_weights(
    const float* __restrict__ Wd1, const float* __restrict__ bd1,
    const float* __restrict__ Wd2, const float* __restrict__ bd2,
    const float* __restrict__ Wc1, const float* __restrict__ bc1,
    const float* __restrict__ Wc2, const float* __restrict__ bc2,
    float* __restrict__ wsf) {
  const int t = threadIdx.x;
  for (int i = t; i < 96; i += NT) wsf[WD1 + i] = Wd1[i];
  for (int i = t; i < 32; i += NT) { wsf[BD1 + i] = bd1[i]; wsf[WD2 + i] = Wd2[i]; }
  if (t == 0) {
    wsf[BD2] = bd2[0];
    wsf[BC2 + 0] = bc2[0]; wsf[BC2 + 1] = bc2[1]; wsf[BC2 + 2] = bc2[2];
  }
  if (t < 32) {
    wsf[NV4 + t * 4 + 0] = bc1[t];
    wsf[NV4 + t * 4 + 1] = Wc1[32 * 32 + t];
    wsf[NV4 + t * 4 + 2] = Wc1[33 * 32 + t];
    wsf[NV4 + t * 4 + 3] = Wc1[34 * 32 + t];
    wsf[W24 + t * 4 + 0] = Wc2[t * 3 + 0];
    wsf[W24 + t * 4 + 1] = Wc2[t * 3 + 1];
    wsf[W24 + t * 4 + 2] = Wc2[t * 3 + 2];
    wsf[W24 + t * 4 + 3] = 0.0f;
  }
  // Wc1[0:32][:] fp16 A-frags: frag[lane*2 + nt]; A[m=n][k], lane: n=nt*16+(lane&15), k=quad*8+j
  if (t < 64) {
    const int q_s = t >> 4;
    uint4* frag = (uint4*)((char*)wsf + WS_FRAG_OFF);
#pragma unroll
    for (int nt = 0; nt < 2; ++nt) {
      const int n_s = nt * 16 + (t & 15);
      uint32_t hw[4];
#pragma unroll
      for (int j2 = 0; j2 < 4; ++j2) {
        const int k = q_s * 8 + j2 * 2;
        hw[j2] = (uint32_t)f2h(Wc1[k * 32 + n_s])
               | ((uint32_t)f2h(Wc1[(k + 1) * 32 + n_s]) << 16);
      }
      frag[t * 2 + nt] = make_uint4(hw[0], hw[1], hw[2], hw[3]);
    }
  }
}

template <bool USE_WS>
__global__ __launch_bounds__(NT, 5) void nerf_fwd(
    const float* __restrict__ hh, const float* __restrict__ ww,
    const float* __restrict__ K, const float* __restrict__ E,
    const float* __restrict__ bg,
    const float* __restrict__ Wd1, const float* __restrict__ bd1,
    const float* __restrict__ Wd2, const float* __restrict__ bd2,
    const float* __restrict__ Wc1, const float* __restrict__ bc1,
    const float* __restrict__ Wc2, const float* __restrict__ bc2,
    const float* __restrict__ wsf,
    float* __restrict__ out, int n_rays) {
  const int ray = blockIdx.x;
  const int t = threadIdx.x;
  const int lane = t & 63;
  const int wv = t >> 6;   // 0 or 1
  const int quad = lane >> 4;

  __shared__ __align__(16) float sw[SWTOT];
  // phase-union: coarse {s_w, s_cdf} then fine H (fp16)
  __shared__ __align__(16) unsigned char u_buf[SF * HSTRIDE * 2];  // 10240 B
  float* const s_w   = (float*)u_buf;
  float* const s_cdf = (float*)(u_buf + 768);
  unsigned short* const s_hf = (unsigned short*)u_buf;
  __shared__ float s_rgb[SF * RGBS];
  __shared__ float s_zlf[SF];
  __shared__ float s_tot[8];
  __shared__ float s_red[16];

  // ---- stage weight image into LDS ----
  if constexpr (USE_WS) {
    const float4* wsrc = (const float4*)wsf;
    float4* sdst = (float4*)sw;
    for (int i = t; i < SWTOT / 4; i += NT) sdst[i] = wsrc[i];
  } else {
    for (int i = t; i < 96; i += NT) sw[WD1 + i] = Wd1[i];
    for (int i = t; i < 32; i += NT) { sw[BD1 + i] = bd1[i]; sw[WD2 + i] = Wd2[i]; }
    if (t == 0) {
      sw[BD2] = bd2[0];
      sw[BC2 + 0] = bc2[0]; sw[BC2 + 1] = bc2[1]; sw[BC2 + 2] = bc2[2];
    }
    if (t < 32) {
      sw[NV4 + t * 4 + 0] = bc1[t];
      sw[NV4 + t * 4 + 1] = Wc1[32 * 32 + t];
      sw[NV4 + t * 4 + 2] = Wc1[33 * 32 + t];
      sw[NV4 + t * 4 + 3] = Wc1[34 * 32 + t];
      sw[W24 + t * 4 + 0] = Wc2[t * 3 + 0];
      sw[W24 + t * 4 + 1] = Wc2[t * 3 + 1];
      sw[W24 + t * 4 + 2] = Wc2[t * 3 + 2];
      sw[W24 + t * 4 + 3] = 0.0f;
    }
  }

  // ---- ray setup (block-uniform) ----
  const float k00 = K[0], k01 = K[1], k02 = K[2];
  const float k10 = K[3], k11 = K[4], k12 = K[5];
  const float k20 = K[6], k21 = K[7], k22 = K[8];
  const float det = k00 * (k11 * k22 - k12 * k21)
                  - k01 * (k10 * k22 - k12 * k20)
                  + k02 * (k10 * k21 - k11 * k20);
  const float id = 1.0f / det;
  const float i00 =  (k11 * k22 - k12 * k21) * id;
  const float i01 = -(k01 * k22 - k02 * k21) * id;
  const float i02 =  (k01 * k12 - k02 * k11) * id;
  const float i10 = -(k10 * k22 - k12 * k20) * id;
  const float i11 =  (k00 * k22 - k02 * k20) * id;
  const float i12 = -(k00 * k12 - k02 * k10) * id;
  const float i20 =  (k10 * k21 - k11 * k20) * id;
  const float i21 = -(k00 * k21 - k01 * k20) * id;
  const float i22 =  (k00 * k11 - k01 * k10) * id;

  const float dwx = ww[ray] + 0.5f;
  const float dwy = hh[ray] + 0.5f;
  const float cx = i00 * dwx + i01 * dwy + i02;
  const float cy = i10 * dwx + i11 * dwy + i12;
  const float cz = i20 * dwx + i21 * dwy + i22;
  const float* Er = E + (size_t)ray * 16;
  const float ox = Er[3], oy = Er[7], oz = Er[11];
  const float dx = Er[0] * cx + Er[1] * cy + Er[2] * cz;
  const float dy = Er[4] * cx + Er[5] * cy + Er[6] * cz;
  const float dz = Er[8] * cx + Er[9] * cy + Er[10] * cz;
  const float inv_nrm = fast_rsq(dx * dx + dy * dy + dz * dz);
  const float ndx = dx * inv_nrm, ndy = dy * inv_nrm, ndz = dz * inv_nrm;

  __syncthreads();   // weights staged

  // ---- coarse pass: e0 = t (all threads); e1 = 128+t (wave 0 only, FUSED loop) ----
  const float bd2v = sw[BD2];
  float v0, v1e = 1.0f;
  {
    float px0, py0, pz0, px1 = 0.f, py1 = 0.f, pz1 = 0.f;
    {
      const float z = exp10_f(zlog_c(t));
      px0 = ox + dx * z; py0 = oy + dy * z; pz0 = oz + dz * z;
      const float dist = sqrtf(px0 * px0 + py0 * py0 + pz0 * pz0);
      if (dist > 1.0f) {
        const float invd = fast_rcp(dist);
        const float sc = (2.0f - invd) * invd;
        px0 *= sc; py0 *= sc; pz0 *= sc;
      }
    }
    if (wv == 0) {
      const float z = exp10_f((float)t * 0.015625f);   // zlog_c(128+t)
      px1 = ox + dx * z; py1 = oy + dy * z; pz1 = oz + dz * z;
      const float dist = sqrtf(px1 * px1 + py1 * py1 + pz1 * pz1);
      if (dist > 1.0f) {
        const float invd = fast_rcp(dist);
        const float sc = (2.0f - invd) * invd;
        px1 *= sc; py1 *= sc; pz1 *= sc;
      }
    }
    // dual accumulators break the 32-deep serial FMA chain
    float acc0a = bd2v, acc0b = 0.0f, acc1a = bd2v, acc1b = 0.0f;
    if (wv == 0) {  // wave-uniform branch: fused 2-sample loop (weights loaded once)
#pragma unroll
      for (int c = 0; c < 8; ++c) {
        const int k4 = c * 4;
        const float4 w0 = ldsf4(sw + WD1 + k4);
        const float4 w1 = ldsf4(sw + WD1 + 32 + k4);
        const float4 w2 = ldsf4(sw + WD1 + 64 + k4);
        const float4 b  = ldsf4(sw + BD1 + k4);
        const float4 wd = ldsf4(sw + WD2 + k4);
        float v;
        v = b.x + px0 * w0.x + py0 * w1.x + pz0 * w2.x; acc0a += fmaxf(v, 0.0f) * wd.x;
        v = b.y + px0 * w0.y + py0 * w1.y + pz0 * w2.y; acc0b += fmaxf(v, 0.0f) * wd.y;
        v = b.z + px0 * w0.z + py0 * w1.z + pz0 * w2.z; acc0a += fmaxf(v, 0.0f) * wd.z;
        v = b.w + px0 * w0.w + py0 * w1.w + pz0 * w2.w; acc0b += fmaxf(v, 0.0f) * wd.w;
        v = b.x + px1 * w0.x + py1 * w1.x + pz1 * w2.x; acc1a += fmaxf(v, 0.0f) * wd.x;
        v = b.y + px1 * w0.y + py1 * w1.y + pz1 * w2.y; acc1b += fmaxf(v, 0.0f) * wd.y;
        v = b.z + px1 * w0.z + py1 * w1.z + pz1 * w2.z; acc1a += fmaxf(v, 0.0f) * wd.z;
        v = b.w + px1 * w0.w + py1 * w1.w + pz1 * w2.w; acc1b += fmaxf(v, 0.0f) * wd.w;
      }
    } else {
#pragma unroll
      for (int c = 0; c < 8; ++c) {
        const int k4 = c * 4;
        const float4 w0 = ldsf4(sw + WD1 + k4);
        const float4 w1 = ldsf4(sw + WD1 + 32 + k4);
        const float4 w2 = ldsf4(sw + WD1 + 64 + k4);
        const float4 b  = ldsf4(sw + BD1 + k4);
        const float4 wd = ldsf4(sw + WD2 + k4);
        float v;
        v = b.x + px0 * w0.x + py0 * w1.x + pz0 * w2.x; acc0a += fmaxf(v, 0.0f) * wd.x;
        v = b.y + px0 * w0.y + py0 * w1.y + pz0 * w2.y; acc0b += fmaxf(v, 0.0f) * wd.y;
        v = b.z + px0 * w0.z + py0 * w1.z + pz0 * w2.z; acc0a += fmaxf(v, 0.0f) * wd.z;
        v = b.w + px0 * w0.w + py0 * w1.w + pz0 * w2.w; acc0b += fmaxf(v, 0.0f) * wd.w;
      }
    }
    v0 = __expf(-softplus_f(acc0a + acc0b) * delta_c(t));
    if (wv == 0) {
      v1e = __expf(-softplus_f(acc1a + acc1b) * delta_c(128 + t));
    }
  }

  // parallel cumprod of (1-alpha) — DPP scan (VALU pipe)
  float i0 = dpp_scan_mul(v0);
  float i1 = 1.0f;
  if (wv == 0) i1 = dpp_scan_mul(v1e);
  if (lane == 63) s_tot[wv] = i0;
  if (wv == 0 && lane == 63) s_tot[2] = i1;
  __syncthreads();
  {
    const float preC1 = s_tot[0];
    const float preC2 = s_tot[0] * s_tot[1];
    // a * exclusive = (1-v)/v * inclusive = (rcp(v)-1) * inclusive  (v in [~0.8, 1])
    s_w[t] = (fast_rcp(v0) - 1.0f) * i0 * (wv ? preC1 : 1.0f);
    if (wv == 0) {
      s_w[128 + t] = (fast_rcp(v1e) - 1.0f) * i1 * preC2;
    }
  }
  __syncthreads();

  // reweight
  float wre0, wre1 = 0.0f;
  {
    const float wm = (t > 0) ? s_w[t - 1] : 0.0f;
    const float w0 = s_w[t];
    const float wp = s_w[t + 1];
    wre0 = 0.5f * (fmaxf(wm, w0) + fmaxf(w0, wp)) + (0.02f / 192.0f);
    wre0 *= (t < 128) ? (128.0f / 192.0f) : (64.0f / 192.0f);
  }
  if (wv == 0) {
    const int e = 128 + t;
    const float wm = s_w[e - 1];
    const float w0 = s_w[e];
    const float wp = (e < SC - 1) ? s_w[e + 1] : 0.0f;
    wre1 = 0.5f * (fmaxf(wm, w0) + fmaxf(w0, wp)) + (0.02f / 192.0f);
    wre1 *= (64.0f / 192.0f);
  }

  // parallel cumsum -> normalized CDF — DPP scan
  float s0 = dpp_scan_add(wre0);
  float s1 = 0.0f;
  if (wv == 0) s1 = dpp_scan_add(wre1);
  if (lane == 63) s_tot[4 + wv] = s0;
  if (wv == 0 && lane == 63) s_tot[6] = s1;
  __syncthreads();
  {
    const float T0 = s_tot[4], T1 = s_tot[5], T2 = s_tot[6];
    const float inv_total = fast_rcp(T0 + T1 + T2);
    s_cdf[t] = (s0 + (wv ? T0 : 0.0f)) * inv_total;
    if (wv == 0) s_cdf[128 + t] = (s1 + T0 + T1) * inv_total;
  }
  __syncthreads();

  // ---- importance sampling ----
  float zlf, zf;
  {
    // 24-ary round-1 probes at FIXED indices: issued before threefry so their
    // LDS latency hides under ~100 VALU cycles of RNG compute.
    float cA[7];
#pragma unroll
    for (int i = 0; i < 7; ++i) cA[i] = s_cdf[24 * i + 24];   // value at m = 24i+23

    const uint32_t total = (uint32_t)n_rays * 128u;
    const uint32_t halfc = total >> 1;
    const uint32_t j = (uint32_t)ray * 128u + (uint32_t)t;
    uint32_t x0, x1;
    const bool first = (j < halfc);
    if (first) { x0 = j; x1 = j + halfc; } else { x0 = j - halfc; x1 = j; }
    threefry2x32_k42(x0, x1);
    const uint32_t bits = first ? x0 : x1;
    const float fr = __uint_as_float((bits >> 9) | 0x3f800000u) - 1.0f;

    float u = (float)t * 0.0078125f + fr * 0.0078125f;
    u = u * (s_cdf[190] - s_cdf[1]) + s_cdf[1];

    // searchsorted(right) over s_cdf[1..189]: lo = #{m in [0,189] : s_cdf[1+m] <= u}
    int start = 0;
#pragma unroll
    for (int i = 0; i < 7; ++i) start += (cA[i] <= u) ? 24 : 0;
    // round 2: 3-ary within the 24-block (probes at m = start+3i+2)
    float cB[7];
#pragma unroll
    for (int i = 0; i < 7; ++i) cB[i] = s_cdf[start + 3 * i + 3];
    int st2 = start;
#pragma unroll
    for (int i = 0; i < 7; ++i) st2 += (cB[i] <= u) ? 3 : 0;
    // round 3: neighborhood fetch (all independent) + cndmask select of cb/ca
    const float p0 = s_cdf[st2];        // value at m = st2-1 (only used if lo==st2)
    const float p1 = s_cdf[st2 + 1];    // m = st2
    const float p2 = s_cdf[st2 + 2];    // m = st2+1
    const float p3 = s_cdf[st2 + 3];    // m = st2+2 (in-union-buffer even at edge)
    const int k = ((p1 <= u) ? 1 : 0) + ((p2 <= u) ? 1 : 0);
    const int lo = st2 + k;
    const int inds = lo + 1;
    const float cb = (k == 0) ? p0 : ((k == 1) ? p1 : p2);
    const float ca = (k == 0) ? p1 : ((k == 1) ? p2 : p3);
    const float tt = (u - cb) * fast_rcp(ca - cb);
    const float zb = 0.5f * (zlog_c(inds - 1) + zlog_c(inds));
    const float za = 0.5f * (zlog_c(inds) + zlog_c(inds + 1));
    zlf = zb + (za - zb) * tt;
    s_zlf[t] = zlf;
    zf = exp10_f(zlf);
  }
  __syncthreads();   // last s_cdf read — union area now free for s_hf

  // ---- Wc1 A-frags (fp16, hi only) ----
  half8 Whi0, Whi1;
  if constexpr (USE_WS) {
    const uint4* frag = (const uint4*)((const char*)wsf + WS_FRAG_OFF);
    uint4 q0 = frag[lane * 2 + 0];
    uint4 q1 = frag[lane * 2 + 1];
    __builtin_memcpy(&Whi0, &q0, 16);
    __builtin_memcpy(&Whi1, &q1, 16);
  } else {
#pragma unroll
    for (int nt = 0; nt < 2; ++nt) {
      const int n_s = nt * 16 + (lane & 15);
      uint32_t hw[4];
#pragma unroll
      for (int j2 = 0; j2 < 4; ++j2) {
        const int k = quad * 8 + j2 * 2;
        hw[j2] = (uint32_t)f2h(Wc1[k * 32 + n_s])
               | ((uint32_t)f2h(Wc1[(k + 1) * 32 + n_s]) << 16);
      }
      uint4 q = make_uint4(hw[0], hw[1], hw[2], hw[3]);
      if (nt == 0) __builtin_memcpy(&Whi0, &q, 16);
      else         __builtin_memcpy(&Whi1, &q, 16);
    }
  }

  // ---- fine density per-thread; h -> LDS as fp16 (HW pack) ----
  float sigf, vf;
  {
    float px = ox + dx * zf, py = oy + dy * zf, pz = oz + dz * zf;
    const float dist = sqrtf(px * px + py * py + pz * pz);
    if (dist > 1.0f) {
      const float invd = fast_rcp(dist);
      const float sc = (2.0f - invd) * invd;
      px *= sc; py *= sc; pz *= sc;
    }
    float siga = bd2v, sigb = 0.0f;
    uint4 tmp;
#pragma unroll
    for (int c = 0; c < 8; ++c) {
      const int k4 = c * 4;
      const float4 w0 = ldsf4(sw + WD1 + k4);
      const float4 w1 = ldsf4(sw + WD1 + 32 + k4);
      const float4 w2 = ldsf4(sw + WD1 + 64 + k4);
      const float4 b  = ldsf4(sw + BD1 + k4);
      const float4 wd = ldsf4(sw + WD2 + k4);
      float h0 = fmaxf(b.x + px * w0.x + py * w1.x + pz * w2.x, 0.0f);
      float h1 = fmaxf(b.y + px * w0.y + py * w1.y + pz * w2.y, 0.0f);
      float h2 = fmaxf(b.z + px * w0.z + py * w1.z + pz * w2.z, 0.0f);
      float h3 = fmaxf(b.w + px * w0.w + py * w1.w + pz * w2.w, 0.0f);
      siga += h0 * wd.x + h2 * wd.z;
      sigb += h1 * wd.y + h3 * wd.w;
      const uint32_t pA = pk2h(h0, h1), pB = pk2h(h2, h3);
      if ((c & 1) == 0) { tmp.x = pA; tmp.y = pB; }
      else {
        tmp.z = pA; tmp.w = pB;
        *(uint4*)(s_hf + t * HSTRIDE + (c >> 1) * 8) = tmp;
      }
    }
    sigf = softplus_f(siga + sigb);
  }
  __syncthreads();   // h staged for MFMA

  // ---- fine color via MFMA: a1^T[32 x 128] = Wc1^T . H^T (fp16) ----
  {
    // per-lane n-values from packed NV4/W24 tables (b128 reads)
    float dvv[2][4], w2v[2][4][3];
#pragma unroll
    for (int nt = 0; nt < 2; ++nt)
#pragma unroll
      for (int r = 0; r < 4; ++r) {
        const int n = nt * 16 + quad * 4 + r;
        const float4 nv = ldsf4(sw + NV4 + n * 4);
        dvv[nt][r] = nv.x + ndx * nv.y + ndy * nv.z + ndz * nv.w;
        const float4 w2 = ldsf4(sw + W24 + n * 4);
        w2v[nt][r][0] = w2.x; w2v[nt][r][1] = w2.y; w2v[nt][r][2] = w2.z;
      }

#pragma unroll
    for (int mt = 0; mt < 4; ++mt) {
      const int sbase = wv * 64 + mt * 16;
      const int srow = sbase + (lane & 15);
      const half8 Hf = *(const half8*)(s_hf + srow * HSTRIDE + quad * 8);

      f32x4 acc0 = {0.f, 0.f, 0.f, 0.f}, acc1 = {0.f, 0.f, 0.f, 0.f};
      acc0 = __builtin_amdgcn_mfma_f32_16x16x32_f16(Whi0, Hf, acc0, 0, 0, 0);
      acc1 = __builtin_amdgcn_mfma_f32_16x16x32_f16(Whi1, Hf, acc1, 0, 0, 0);

      float pc0 = 0.f, pc1 = 0.f, pc2 = 0.f;
#pragma unroll
      for (int r = 0; r < 4; ++r) {
        const float av0 = fmaxf(acc0[r] + dvv[0][r], 0.0f);
        const float av1 = fmaxf(acc1[r] + dvv[1][r], 0.0f);
        pc0 += av0 * w2v[0][r][0] + av1 * w2v[1][r][0];
        pc1 += av0 * w2v[0][r][1] + av1 * w2v[1][r][1];
        pc2 += av0 * w2v[0][r][2] + av1 * w2v[1][r][2];
      }
#pragma unroll
      for (int mask = 16; mask < 64; mask <<= 1) {
        pc0 += __shfl_xor(pc0, mask, 64);
        pc1 += __shfl_xor(pc1, mask, 64);
        pc2 += __shfl_xor(pc2, mask, 64);
      }
      const int cidx = lane >> 4;
      const float oc = (cidx == 0) ? pc0 : ((cidx == 1) ? pc1 : pc2);
      if (lane < 48) {
        const int s = sbase + (lane & 15);
        const float o = oc + sw[BC2 + cidx];
        s_rgb[s * RGBS + cidx] = fast_rcp(1.0f + __expf(-o));
      }
    }
  }

  // ---- fine alpha + parallel cumprod over 128 (DPP scan) ----
  const float deltaf = (t < SF - 1) ? (s_zlf[t + 1] - zlf) : 0.0f;
  vf = __expf(-sigf * deltaf);
  float fi = dpp_scan_mul(vf);
  if (lane == 63) s_tot[wv] = fi;
  __syncthreads();   // also makes s_rgb visible
  const float wf = (fast_rcp(vf) - 1.0f) * fi * (wv ? s_tot[0] : 1.0f);

  // ---- outputs ----
  float* o_img = out;
  float* o_w   = out + (size_t)n_rays * 3;
  float* o_z   = out + (size_t)n_rays * (3 + 128);
  float* o_inv = out + (size_t)n_rays * (3 + 256);

  o_w[(size_t)ray * 128 + t] = wf;
  o_z[(size_t)ray * 128 + t] = (zlf + 1.0f) * 0.5f;

  float r0 = wf * s_rgb[t * RGBS + 0];
  float r1 = wf * s_rgb[t * RGBS + 1];
  float r2 = wf * s_rgb[t * RGBS + 2];
  float r3 = wf, r4 = wf * fast_rcp(zf);
  // DPP scan-based reduce: lane 63 holds the wave total
  r0 = dpp_scan_add(r0);
  r1 = dpp_scan_add(r1);
  r2 = dpp_scan_add(r2);
  r3 = dpp_scan_add(r3);
  r4 = dpp_scan_add(r4);
  if (lane == 63) {
    float* p = &s_red[wv * 5];
    p[0] = r0; p[1] = r1; p[2] = r2; p[3] = r3; p[4] = r4;
  }
  __syncthreads();
  if (t == 0) {
    const float accw = s_red[3] + s_red[8];
    const float bgw = 1.0f - accw;
    o_img[(size_t)ray * 3 + 0] = (s_red[0] + s_red[5]) + bgw * bg[0];
    o_img[(size_t)ray * 3 + 1] = (s_red[1] + s_red[6]) + bgw * bg[1];
    o_img[(size_t)ray * 3 + 2] = (s_red[2] + s_red[7]) + bgw * bg[2];
    o_inv[ray] = s_red[4] + s_red[9];
  }
}

extern "C" void kernel_launch(void* const* d_in, const int* in_sizes, int n_in,
                              void* d_out, int out_size, void* d_ws, size_t ws_size,
                              hipStream_t stream) {
  const float* h   = (const float*)d_in[1];
  const float* w   = (const float*)d_in[2];
  const float* K   = (const float*)d_in[3];
  const float* E   = (const float*)d_in[4];
  const float* bg  = (const float*)d_in[5];
  const float* Wd1 = (const float*)d_in[6];
  const float* bd1 = (const float*)d_in[7];
  const float* Wd2 = (const float*)d_in[8];
  const float* bd2 = (const float*)d_in[9];
  const float* Wc1 = (const float*)d_in[10];
  const float* bc1 = (const float*)d_in[11];
  const float* Wc2 = (const float*)d_in[12];
  const float* bc2 = (const float*)d_in[13];
  const int n_rays = in_sizes[1];
  float* wsf = (float*)d_ws;

  if (ws_size >= WS_NEED) {
    pack_weights<<<1, NT, 0, stream>>>(Wd1, bd1, Wd2, bd2, Wc1, bc1, Wc2, bc2, wsf);
    nerf_fwd<true><<<n_rays, NT, 0, stream>>>(h, w, K, E, bg, Wd1, bd1, Wd2, bd2,
                                              Wc1, bc1, Wc2, bc2, wsf,
                                              (float*)d_out, n_rays);
  } else {
    nerf_fwd<false><<<n_rays, NT, 0, stream>>>(h, w, K, E, bg, Wd1, bd1, Wd2, bd2,
                                               Wc1, bc1, Wc2, bc2, nullptr,
                                               (float*)d_out, n_rays);
  }
}

// Round 2
// 150.062 us; speedup vs baseline: 1.1233x; 1.0386x over previous
//
#include <hip/hip_runtime.h>
#include <stdint.h>

#define SC 192      // coarse samples (128 + 64)
#define SF 128      // fine (importance) samples
#define NT 128      // threads per block = 2 waves

// LDS weight-image offsets (floats)
#define WD1   0     // 96  (3x32 row-major)
#define BD1   96    // 32
#define WD2   128   // 32
#define BD2   160   // 1
#define BC2   161   // 3
#define NV4   164   // 32 x float4: (bc1[n], Wc1[32][n], Wc1[33][n], Wc1[34][n])
#define SWS   292   // staged floats (73 float4s)

#define KINV  296   // ws float offset: 9 floats, row-major inv(K)
#define WS_FRAG_OFF  2048   // byte offset of Wc1 fp16 A-frags in d_ws (2048 B)
#define WS_FRAG2_OFF 4096   // byte offset of Wc2 fp16 A-frag (1024 B)
#define WS_NEED      6144

#define HSTRIDE 40  // ushort stride for H rows (80 B rows -> bank-friendly)
#define RGBS 4

using half8 = __attribute__((ext_vector_type(8))) _Float16;
using f32x4 = __attribute__((ext_vector_type(4))) float;
using f32x2 = __attribute__((ext_vector_type(2))) float;

#define LO2(v) __builtin_shufflevector(v, v, 0, 1)
#define HI2(v) __builtin_shufflevector(v, v, 2, 3)

__device__ __forceinline__ float zlog_c(int t) {
  return (t < 128) ? (-1.0f + (float)t * 0.0078125f)
                   : ((float)(t - 128) * 0.015625f);
}
__device__ __forceinline__ float delta_c(int t) {
  if (t >= SC - 1) return 0.0f;
  return zlog_c(t + 1) - zlog_c(t);
}

__device__ __forceinline__ float fast_rcp(float x) { return __builtin_amdgcn_rcpf(x); }
__device__ __forceinline__ float fast_rsq(float x) { return __builtin_amdgcn_rsqf(x); }
__device__ __forceinline__ float exp10_f(float x) { return __expf(x * 2.30258509299f); }
__device__ __forceinline__ float softplus_f(float x) {
  return fmaxf(x, 0.0f) + __logf(1.0f + __expf(-fabsf(x)));
}

// v_pk_fma_f32: 2x fp32 FMA in one VOP3P instruction (identical fma rounding)
__device__ __forceinline__ f32x2 pk_fma(f32x2 a, f32x2 b, f32x2 c) {
  f32x2 d;
  asm("v_pk_fma_f32 %0, %1, %2, %3" : "=v"(d) : "v"(a), "v"(b), "v"(c));
  return d;
}

// fp16 helpers: pk2h = 1 HW instr (v_cvt_pkrtz_f16_f32); f2h = RTN scalar convert
__device__ __forceinline__ uint32_t pk2h(float a, float b) {
  auto p = __builtin_amdgcn_cvt_pkrtz(a, b);
  uint32_t u; __builtin_memcpy(&u, &p, 4); return u;
}
__device__ __forceinline__ unsigned short f2h(float f) {
  _Float16 h = (_Float16)f;
  unsigned short us; __builtin_memcpy(&us, &h, 2); return us;
}

__device__ __forceinline__ float4 ldsf4(const float* p) { return *(const float4*)p; }
__device__ __forceinline__ f32x4 ldsv4(const float* p) { return *(const f32x4*)p; }

// ---- DPP cross-lane (VALU pipe, no LDS): gfx9 row_shr / row_bcast sequence ----
template <int CTRL, int RMASK, int BMASK>
__device__ __forceinline__ float dpp_mov(float x, float oldv) {
  return __int_as_float(__builtin_amdgcn_update_dpp(
      __float_as_int(oldv), __float_as_int(x), CTRL, RMASK, BMASK, false));
}
__device__ __forceinline__ float dpp_scan_add(float v) {
  v += dpp_mov<0x111, 0xf, 0xf>(v, 0.0f);   // row_shr:1
  v += dpp_mov<0x112, 0xf, 0xf>(v, 0.0f);   // row_shr:2
  v += dpp_mov<0x114, 0xf, 0xf>(v, 0.0f);   // row_shr:4
  v += dpp_mov<0x118, 0xf, 0xf>(v, 0.0f);   // row_shr:8
  v += dpp_mov<0x142, 0xa, 0xf>(v, 0.0f);   // row_bcast:15 -> rows 1,3
  v += dpp_mov<0x143, 0xc, 0xf>(v, 0.0f);   // row_bcast:31 -> rows 2,3
  return v;
}
__device__ __forceinline__ float dpp_scan_mul(float v) {
  v *= dpp_mov<0x111, 0xf, 0xf>(v, 1.0f);
  v *= dpp_mov<0x112, 0xf, 0xf>(v, 1.0f);
  v *= dpp_mov<0x114, 0xf, 0xf>(v, 1.0f);
  v *= dpp_mov<0x118, 0xf, 0xf>(v, 1.0f);
  v *= dpp_mov<0x142, 0xa, 0xf>(v, 1.0f);
  v *= dpp_mov<0x143, 0xc, 0xf>(v, 1.0f);
  return v;
}

// JAX threefry2x32 with key = (0, 42)
__device__ __forceinline__ void threefry2x32_k42(uint32_t& x0, uint32_t& x1) {
  const uint32_t ks0 = 0u, ks1 = 42u;
  const uint32_t ks2 = ks0 ^ ks1 ^ 0x1BD11BDAu;
  const uint32_t ks[3] = {ks0, ks1, ks2};
  const int rot[2][4] = {{13, 15, 26, 6}, {17, 29, 16, 24}};
  x0 += ks[0];
  x1 += ks[1];
#pragma unroll
  for (int i = 0; i < 5; ++i) {
#pragma unroll
    for (int j = 0; j < 4; ++j) {
      x0 += x1;
      const int r = rot[i & 1][j];
      x1 = (x1 << r) | (x1 >> (32 - r));
      x1 ^= x0;
    }
    x0 += ks[(i + 1) % 3];
    x1 += ks[(i + 2) % 3] + (uint32_t)(i + 1);
  }
}

// ---- pre-pack kernel: weight image + K-inverse + fp16 A-frags ----
__global__ __launch_bounds__(NT) void pack_weights(
    const float* __restrict__ K,
    const float* __restrict__ Wd1, const float* __restrict__ bd1,
    const float* __restrict__ Wd2, const float* __restrict__ bd2,
    const float* __restrict__ Wc1, const float* __restrict__ bc1,
    const float* __restrict__ Wc2, const float* __restrict__ bc2,
    float* __restrict__ wsf) {
  const int t = threadIdx.x;
  for (int i = t; i < 96; i += NT) wsf[WD1 + i] = Wd1[i];
  for (int i = t; i < 32; i += NT) { wsf[BD1 + i] = bd1[i]; wsf[WD2 + i] = Wd2[i]; }
  if (t == 0) {
    wsf[BD2] = bd2[0];
    wsf[BC2 + 0] = bc2[0]; wsf[BC2 + 1] = bc2[1]; wsf[BC2 + 2] = bc2[2];
    // K-inverse (ray-independent)
    const float k00 = K[0], k01 = K[1], k02 = K[2];
    const float k10 = K[3], k11 = K[4], k12 = K[5];
    const float k20 = K[6], k21 = K[7], k22 = K[8];
    const float det = k00 * (k11 * k22 - k12 * k21)
                    - k01 * (k10 * k22 - k12 * k20)
                    + k02 * (k10 * k21 - k11 * k20);
    const float id = 1.0f / det;
    wsf[KINV + 0] =  (k11 * k22 - k12 * k21) * id;
    wsf[KINV + 1] = -(k01 * k22 - k02 * k21) * id;
    wsf[KINV + 2] =  (k01 * k12 - k02 * k11) * id;
    wsf[KINV + 3] = -(k10 * k22 - k12 * k20) * id;
    wsf[KINV + 4] =  (k00 * k22 - k02 * k20) * id;
    wsf[KINV + 5] = -(k00 * k12 - k02 * k10) * id;
    wsf[KINV + 6] =  (k10 * k21 - k11 * k20) * id;
    wsf[KINV + 7] = -(k00 * k21 - k01 * k20) * id;
    wsf[KINV + 8] =  (k00 * k11 - k01 * k10) * id;
  }
  if (t < 32) {
    wsf[NV4 + t * 4 + 0] = bc1[t];
    wsf[NV4 + t * 4 + 1] = Wc1[32 * 32 + t];
    wsf[NV4 + t * 4 + 2] = Wc1[33 * 32 + t];
    wsf[NV4 + t * 4 + 3] = Wc1[34 * 32 + t];
  }
  // Wc1[0:32][:] fp16 A-frags: frag[lane*2 + nt]; A[m=n][k], lane: n=nt*16+(lane&15), k=quad*8+j
  if (t < 64) {
    const int q_s = t >> 4;
    uint4* frag = (uint4*)((char*)wsf + WS_FRAG_OFF);
#pragma unroll
    for (int nt = 0; nt < 2; ++nt) {
      const int n_s = nt * 16 + (t & 15);
      uint32_t hw[4];
#pragma unroll
      for (int j2 = 0; j2 < 4; ++j2) {
        const int k = q_s * 8 + j2 * 2;
        hw[j2] = (uint32_t)f2h(Wc1[k * 32 + n_s])
               | ((uint32_t)f2h(Wc1[(k + 1) * 32 + n_s]) << 16);
      }
      frag[t * 2 + nt] = make_uint4(hw[0], hw[1], hw[2], hw[3]);
    }
    // Wc2 A-frag for layer-2 MFMA, k-permuted to match layer-1 C layout:
    // position k = q*8+j holds hidden h = (j<4 ? q*4+j : 16+q*4+(j-4)); rows m>=3 are 0
    {
      const int m = t & 15, q = t >> 4;
      uint32_t hw2[4];
#pragma unroll
      for (int jp = 0; jp < 4; ++jp) {
        const int j0 = jp * 2, j1 = j0 + 1;
        const int ha = (j0 < 4) ? q * 4 + j0 : 16 + q * 4 + (j0 - 4);
        const int hb = (j1 < 4) ? q * 4 + j1 : 16 + q * 4 + (j1 - 4);
        const float va = (m < 3) ? Wc2[ha * 3 + m] : 0.0f;
        const float vb = (m < 3) ? Wc2[hb * 3 + m] : 0.0f;
        hw2[jp] = (uint32_t)f2h(va) | ((uint32_t)f2h(vb) << 16);
      }
      ((uint4*)((char*)wsf + WS_FRAG2_OFF))[t] = make_uint4(hw2[0], hw2[1], hw2[2], hw2[3]);
    }
  }
}

template <bool USE_WS>
__global__ __launch_bounds__(NT, 5) void nerf_fwd(
    const float* __restrict__ hh, const float* __restrict__ ww,
    const float* __restrict__ K, const float* __restrict__ E,
    const float* __restrict__ bg,
    const float* __restrict__ Wd1, const float* __restrict__ bd1,
    const float* __restrict__ Wd2, const float* __restrict__ bd2,
    const float* __restrict__ Wc1, const float* __restrict__ bc1,
    const float* __restrict__ Wc2, const float* __restrict__ bc2,
    const float* __restrict__ wsf,
    float* __restrict__ out, int n_rays) {
  const int ray = blockIdx.x;
  const int t = threadIdx.x;
  const int lane = t & 63;
  const int wv = t >> 6;   // 0 or 1
  const int quad = lane >> 4;

  __shared__ __align__(16) float sw[SWS];
  // phase-union: coarse {s_w, s_cdf} then fine H (fp16)
  __shared__ __align__(16) unsigned char u_buf[SF * HSTRIDE * 2];  // 10240 B
  float* const s_w   = (float*)u_buf;
  float* const s_cdf = (float*)(u_buf + 768);
  unsigned short* const s_hf = (unsigned short*)u_buf;
  __shared__ float s_rgb[SF * RGBS];
  __shared__ float s_zlf[SF];
  __shared__ float s_tot[8];
  __shared__ float s_red[16];

  // ---- stage weight image into LDS ----
  if constexpr (USE_WS) {
    const float4* wsrc = (const float4*)wsf;
    float4* sdst = (float4*)sw;
    for (int i = t; i < SWS / 4; i += NT) sdst[i] = wsrc[i];
  } else {
    for (int i = t; i < 96; i += NT) sw[WD1 + i] = Wd1[i];
    for (int i = t; i < 32; i += NT) { sw[BD1 + i] = bd1[i]; sw[WD2 + i] = Wd2[i]; }
    if (t == 0) {
      sw[BD2] = bd2[0];
      sw[BC2 + 0] = bc2[0]; sw[BC2 + 1] = bc2[1]; sw[BC2 + 2] = bc2[2];
    }
    if (t < 32) {
      sw[NV4 + t * 4 + 0] = bc1[t];
      sw[NV4 + t * 4 + 1] = Wc1[32 * 32 + t];
      sw[NV4 + t * 4 + 2] = Wc1[33 * 32 + t];
      sw[NV4 + t * 4 + 3] = Wc1[34 * 32 + t];
    }
  }

  // ---- ray setup (block-uniform) ----
  float i00, i01, i02, i10, i11, i12, i20, i21, i22;
  if constexpr (USE_WS) {
    i00 = wsf[KINV + 0]; i01 = wsf[KINV + 1]; i02 = wsf[KINV + 2];
    i10 = wsf[KINV + 3]; i11 = wsf[KINV + 4]; i12 = wsf[KINV + 5];
    i20 = wsf[KINV + 6]; i21 = wsf[KINV + 7]; i22 = wsf[KINV + 8];
  } else {
    const float k00 = K[0], k01 = K[1], k02 = K[2];
    const float k10 = K[3], k11 = K[4], k12 = K[5];
    const float k20 = K[6], k21 = K[7], k22 = K[8];
    const float det = k00 * (k11 * k22 - k12 * k21)
                    - k01 * (k10 * k22 - k12 * k20)
                    + k02 * (k10 * k21 - k11 * k20);
    const float id = 1.0f / det;
    i00 =  (k11 * k22 - k12 * k21) * id;
    i01 = -(k01 * k22 - k02 * k21) * id;
    i02 =  (k01 * k12 - k02 * k11) * id;
    i10 = -(k10 * k22 - k12 * k20) * id;
    i11 =  (k00 * k22 - k02 * k20) * id;
    i12 = -(k00 * k12 - k02 * k10) * id;
    i20 =  (k10 * k21 - k11 * k20) * id;
    i21 = -(k00 * k21 - k01 * k20) * id;
    i22 =  (k00 * k11 - k01 * k10) * id;
  }

  const float dwx = ww[ray] + 0.5f;
  const float dwy = hh[ray] + 0.5f;
  const float cx = i00 * dwx + i01 * dwy + i02;
  const float cy = i10 * dwx + i11 * dwy + i12;
  const float cz = i20 * dwx + i21 * dwy + i22;
  const float* Er = E + (size_t)ray * 16;
  const float ox = Er[3], oy = Er[7], oz = Er[11];
  const float dx = Er[0] * cx + Er[1] * cy + Er[2] * cz;
  const float dy = Er[4] * cx + Er[5] * cy + Er[6] * cz;
  const float dz = Er[8] * cx + Er[9] * cy + Er[10] * cz;
  const float inv_nrm = fast_rsq(dx * dx + dy * dy + dz * dz);
  const float ndx = dx * inv_nrm, ndy = dy * inv_nrm, ndz = dz * inv_nrm;

  __syncthreads();   // weights staged

  // ---- coarse pass: e0 = t (all threads); e1 = 128+t (wave 0 only, FUSED loop) ----
  const float bd2v = sw[BD2];
  float v0, v1e = 1.0f;
  {
    float px0, py0, pz0, px1 = 0.f, py1 = 0.f, pz1 = 0.f;
    {
      const float z = exp10_f(zlog_c(t));
      px0 = ox + dx * z; py0 = oy + dy * z; pz0 = oz + dz * z;
      const float d2 = px0 * px0 + py0 * py0 + pz0 * pz0;
      if (d2 > 1.0f) {
        const float invd = fast_rsq(d2);
        const float sc = (2.0f - invd) * invd;
        px0 *= sc; py0 *= sc; pz0 *= sc;
      }
    }
    if (wv == 0) {
      const float z = exp10_f((float)t * 0.015625f);   // zlog_c(128+t)
      px1 = ox + dx * z; py1 = oy + dy * z; pz1 = oz + dz * z;
      const float d2 = px1 * px1 + py1 * py1 + pz1 * pz1;
      if (d2 > 1.0f) {
        const float invd = fast_rsq(d2);
        const float sc = (2.0f - invd) * invd;
        px1 *= sc; py1 *= sc; pz1 *= sc;
      }
    }
    // packed dual-FMA over hidden-unit pairs; acc halves keep the even/odd-unit
    // grouping of the previous dual accumulators (bitwise-identical density)
    const f32x2 px0p = {px0, px0}, py0p = {py0, py0}, pz0p = {pz0, pz0};
    f32x2 a0P = {bd2v, 0.0f};
    if (wv == 0) {  // wave-uniform branch: fused 2-sample loop (weights loaded once)
      const f32x2 px1p = {px1, px1}, py1p = {py1, py1}, pz1p = {pz1, pz1};
      f32x2 a1P = {bd2v, 0.0f};
#pragma unroll
      for (int c = 0; c < 8; ++c) {
        const int k4 = c * 4;
        const f32x4 w0 = ldsv4(sw + WD1 + k4);
        const f32x4 w1 = ldsv4(sw + WD1 + 32 + k4);
        const f32x4 w2 = ldsv4(sw + WD1 + 64 + k4);
        const f32x4 b  = ldsv4(sw + BD1 + k4);
        const f32x4 wd = ldsv4(sw + WD2 + k4);
        f32x2 v, h;
        v = pk_fma(pz0p, LO2(w2), pk_fma(py0p, LO2(w1), pk_fma(px0p, LO2(w0), LO2(b))));
        h.x = fmaxf(v.x, 0.0f); h.y = fmaxf(v.y, 0.0f);
        a0P = pk_fma(h, LO2(wd), a0P);
        v = pk_fma(pz0p, HI2(w2), pk_fma(py0p, HI2(w1), pk_fma(px0p, HI2(w0), HI2(b))));
        h.x = fmaxf(v.x, 0.0f); h.y = fmaxf(v.y, 0.0f);
        a0P = pk_fma(h, HI2(wd), a0P);
        v = pk_fma(pz1p, LO2(w2), pk_fma(py1p, LO2(w1), pk_fma(px1p, LO2(w0), LO2(b))));
        h.x = fmaxf(v.x, 0.0f); h.y = fmaxf(v.y, 0.0f);
        a1P = pk_fma(h, LO2(wd), a1P);
        v = pk_fma(pz1p, HI2(w2), pk_fma(py1p, HI2(w1), pk_fma(px1p, HI2(w0), HI2(b))));
        h.x = fmaxf(v.x, 0.0f); h.y = fmaxf(v.y, 0.0f);
        a1P = pk_fma(h, HI2(wd), a1P);
      }
      v1e = __expf(-softplus_f(a1P.x + a1P.y) * delta_c(128 + t));
    } else {
#pragma unroll
      for (int c = 0; c < 8; ++c) {
        const int k4 = c * 4;
        const f32x4 w0 = ldsv4(sw + WD1 + k4);
        const f32x4 w1 = ldsv4(sw + WD1 + 32 + k4);
        const f32x4 w2 = ldsv4(sw + WD1 + 64 + k4);
        const f32x4 b  = ldsv4(sw + BD1 + k4);
        const f32x4 wd = ldsv4(sw + WD2 + k4);
        f32x2 v, h;
        v = pk_fma(pz0p, LO2(w2), pk_fma(py0p, LO2(w1), pk_fma(px0p, LO2(w0), LO2(b))));
        h.x = fmaxf(v.x, 0.0f); h.y = fmaxf(v.y, 0.0f);
        a0P = pk_fma(h, LO2(wd), a0P);
        v = pk_fma(pz0p, HI2(w2), pk_fma(py0p, HI2(w1), pk_fma(px0p, HI2(w0), HI2(b))));
        h.x = fmaxf(v.x, 0.0f); h.y = fmaxf(v.y, 0.0f);
        a0P = pk_fma(h, HI2(wd), a0P);
      }
    }
    v0 = __expf(-softplus_f(a0P.x + a0P.y) * delta_c(t));
  }

  // parallel cumprod of (1-alpha) — DPP scan (VALU pipe)
  float i0 = dpp_scan_mul(v0);
  float i1 = 1.0f;
  if (wv == 0) i1 = dpp_scan_mul(v1e);
  if (lane == 63) s_tot[wv] = i0;
  if (wv == 0 && lane == 63) s_tot[2] = i1;
  __syncthreads();
  {
    const float preC1 = s_tot[0];
    const float preC2 = s_tot[0] * s_tot[1];
    // a * exclusive = (1-v)/v * inclusive = (rcp(v)-1) * inclusive
    s_w[t] = (fast_rcp(v0) - 1.0f) * i0 * (wv ? preC1 : 1.0f);
    if (wv == 0) {
      s_w[128 + t] = (fast_rcp(v1e) - 1.0f) * i1 * preC2;
    }
  }
  __syncthreads();

  // reweight
  float wre0, wre1 = 0.0f;
  {
    const float wm = (t > 0) ? s_w[t - 1] : 0.0f;
    const float w0 = s_w[t];
    const float wp = s_w[t + 1];
    wre0 = 0.5f * (fmaxf(wm, w0) + fmaxf(w0, wp)) + (0.02f / 192.0f);
    wre0 *= (t < 128) ? (128.0f / 192.0f) : (64.0f / 192.0f);
  }
  if (wv == 0) {
    const int e = 128 + t;
    const float wm = s_w[e - 1];
    const float w0 = s_w[e];
    const float wp = (e < SC - 1) ? s_w[e + 1] : 0.0f;
    wre1 = 0.5f * (fmaxf(wm, w0) + fmaxf(w0, wp)) + (0.02f / 192.0f);
    wre1 *= (64.0f / 192.0f);
  }

  // parallel cumsum -> normalized CDF — DPP scan
  float s0 = dpp_scan_add(wre0);
  float s1 = 0.0f;
  if (wv == 0) s1 = dpp_scan_add(wre1);
  if (lane == 63) s_tot[4 + wv] = s0;
  if (wv == 0 && lane == 63) s_tot[6] = s1;
  __syncthreads();
  {
    const float T0 = s_tot[4], T1 = s_tot[5], T2 = s_tot[6];
    const float inv_total = fast_rcp(T0 + T1 + T2);
    s_cdf[t] = (s0 + (wv ? T0 : 0.0f)) * inv_total;
    if (wv == 0) s_cdf[128 + t] = (s1 + T0 + T1) * inv_total;
  }
  __syncthreads();

  // ---- importance sampling ----
  float zlf, zf;
  {
    // 24-ary round-1 probes at FIXED indices: issued before threefry so their
    // LDS latency hides under ~100 VALU cycles of RNG compute.
    float cA[7];
#pragma unroll
    for (int i = 0; i < 7; ++i) cA[i] = s_cdf[24 * i + 24];   // value at m = 24i+23

    const uint32_t total = (uint32_t)n_rays * 128u;
    const uint32_t halfc = total >> 1;
    const uint32_t j = (uint32_t)ray * 128u + (uint32_t)t;
    uint32_t x0, x1;
    const bool first = (j < halfc);
    if (first) { x0 = j; x1 = j + halfc; } else { x0 = j - halfc; x1 = j; }
    threefry2x32_k42(x0, x1);
    const uint32_t bits = first ? x0 : x1;
    const float fr = __uint_as_float((bits >> 9) | 0x3f800000u) - 1.0f;

    float u = (float)t * 0.0078125f + fr * 0.0078125f;
    u = u * (s_cdf[190] - s_cdf[1]) + s_cdf[1];

    // searchsorted(right) over s_cdf[1..189]: lo = #{m in [0,189] : s_cdf[1+m] <= u}
    int start = 0;
#pragma unroll
    for (int i = 0; i < 7; ++i) start += (cA[i] <= u) ? 24 : 0;
    // round 2: 3-ary within the 24-block (probes at m = start+3i+2)
    float cB[7];
#pragma unroll
    for (int i = 0; i < 7; ++i) cB[i] = s_cdf[start + 3 * i + 3];
    int st2 = start;
#pragma unroll
    for (int i = 0; i < 7; ++i) st2 += (cB[i] <= u) ? 3 : 0;
    // round 3: neighborhood fetch (all independent) + cndmask select of cb/ca
    const float p0 = s_cdf[st2];
    const float p1 = s_cdf[st2 + 1];
    const float p2 = s_cdf[st2 + 2];
    const float p3 = s_cdf[st2 + 3];
    const int k = ((p1 <= u) ? 1 : 0) + ((p2 <= u) ? 1 : 0);
    const int lo = st2 + k;
    const int inds = lo + 1;
    const float cb = (k == 0) ? p0 : ((k == 1) ? p1 : p2);
    const float ca = (k == 0) ? p1 : ((k == 1) ? p2 : p3);
    const float tt = (u - cb) * fast_rcp(ca - cb);
    const float zb = 0.5f * (zlog_c(inds - 1) + zlog_c(inds));
    const float za = 0.5f * (zlog_c(inds) + zlog_c(inds + 1));
    zlf = zb + (za - zb) * tt;
    s_zlf[t] = zlf;
    zf = exp10_f(zlf);
  }
  __syncthreads();   // last s_cdf read — union area now free for s_hf

  // ---- Wc1 + Wc2 A-frags (fp16) ----
  half8 Whi0, Whi1, W2f;
  if constexpr (USE_WS) {
    const uint4* frag = (const uint4*)((const char*)wsf + WS_FRAG_OFF);
    uint4 q0 = frag[lane * 2 + 0];
    uint4 q1 = frag[lane * 2 + 1];
    uint4 q2 = ((const uint4*)((const char*)wsf + WS_FRAG2_OFF))[lane];
    __builtin_memcpy(&Whi0, &q0, 16);
    __builtin_memcpy(&Whi1, &q1, 16);
    __builtin_memcpy(&W2f, &q2, 16);
  } else {
#pragma unroll
    for (int nt = 0; nt < 2; ++nt) {
      const int n_s = nt * 16 + (lane & 15);
      uint32_t hw[4];
#pragma unroll
      for (int j2 = 0; j2 < 4; ++j2) {
        const int k = quad * 8 + j2 * 2;
        hw[j2] = (uint32_t)f2h(Wc1[k * 32 + n_s])
               | ((uint32_t)f2h(Wc1[(k + 1) * 32 + n_s]) << 16);
      }
      uint4 q = make_uint4(hw[0], hw[1], hw[2], hw[3]);
      if (nt == 0) __builtin_memcpy(&Whi0, &q, 16);
      else         __builtin_memcpy(&Whi1, &q, 16);
    }
    {
      const int m = lane & 15;
      uint32_t hw2[4];
#pragma unroll
      for (int jp = 0; jp < 4; ++jp) {
        const int j0 = jp * 2, j1 = j0 + 1;
        const int ha = (j0 < 4) ? quad * 4 + j0 : 16 + quad * 4 + (j0 - 4);
        const int hb = (j1 < 4) ? quad * 4 + j1 : 16 + quad * 4 + (j1 - 4);
        const float va = (m < 3) ? Wc2[ha * 3 + m] : 0.0f;
        const float vb = (m < 3) ? Wc2[hb * 3 + m] : 0.0f;
        hw2[jp] = (uint32_t)f2h(va) | ((uint32_t)f2h(vb) << 16);
      }
      uint4 q2 = make_uint4(hw2[0], hw2[1], hw2[2], hw2[3]);
      __builtin_memcpy(&W2f, &q2, 16);
    }
  }

  // ---- fine density per-thread; h -> LDS as fp16 (HW pack) ----
  float sigf, vf;
  {
    float px = ox + dx * zf, py = oy + dy * zf, pz = oz + dz * zf;
    const float d2 = px * px + py * py + pz * pz;
    if (d2 > 1.0f) {
      const float invd = fast_rsq(d2);
      const float sc = (2.0f - invd) * invd;
      px *= sc; py *= sc; pz *= sc;
    }
    const f32x2 pxp = {px, px}, pyp = {py, py}, pzp = {pz, pz};
    f32x2 sP = {bd2v, 0.0f};
    uint4 tmp;
#pragma unroll
    for (int c = 0; c < 8; ++c) {
      const int k4 = c * 4;
      const f32x4 w0 = ldsv4(sw + WD1 + k4);
      const f32x4 w1 = ldsv4(sw + WD1 + 32 + k4);
      const f32x4 w2 = ldsv4(sw + WD1 + 64 + k4);
      const f32x4 b  = ldsv4(sw + BD1 + k4);
      const f32x4 wd = ldsv4(sw + WD2 + k4);
      f32x2 v, hlo, hhi;
      v = pk_fma(pzp, LO2(w2), pk_fma(pyp, LO2(w1), pk_fma(pxp, LO2(w0), LO2(b))));
      hlo.x = fmaxf(v.x, 0.0f); hlo.y = fmaxf(v.y, 0.0f);
      sP = pk_fma(hlo, LO2(wd), sP);
      v = pk_fma(pzp, HI2(w2), pk_fma(pyp, HI2(w1), pk_fma(pxp, HI2(w0), HI2(b))));
      hhi.x = fmaxf(v.x, 0.0f); hhi.y = fmaxf(v.y, 0.0f);
      sP = pk_fma(hhi, HI2(wd), sP);
      const uint32_t pA = pk2h(hlo.x, hlo.y), pB = pk2h(hhi.x, hhi.y);
      if ((c & 1) == 0) { tmp.x = pA; tmp.y = pB; }
      else {
        tmp.z = pA; tmp.w = pB;
        *(uint4*)(s_hf + t * HSTRIDE + (c >> 1) * 8) = tmp;
      }
    }
    sigf = softplus_f(sP.x + sP.y);
  }
  __syncthreads();   // h staged for MFMA

  // ---- fine color via MFMA chain: a1 = Wc1^T.H (dv in acc), rgb = Wc2^T.relu(a1) ----
  {
    // per-lane dv values (block-uniform per hidden unit) -> layer-1 acc init
    float dvv[2][4];
#pragma unroll
    for (int nt = 0; nt < 2; ++nt)
#pragma unroll
      for (int r = 0; r < 4; ++r) {
        const int n = nt * 16 + quad * 4 + r;
        const float4 nv = ldsf4(sw + NV4 + n * 4);
        dvv[nt][r] = nv.x + ndx * nv.y + ndy * nv.z + ndz * nv.w;
      }
    // layer-2 acc init: bias bc2 on quad0 rows 0..2
    f32x4 c2init;
    {
      const float b0 = sw[BC2 + 0], b1 = sw[BC2 + 1], b2 = sw[BC2 + 2];
      const bool q0 = (quad == 0);
      c2init[0] = q0 ? b0 : 0.0f;
      c2init[1] = q0 ? b1 : 0.0f;
      c2init[2] = q0 ? b2 : 0.0f;
      c2init[3] = 0.0f;
    }

#pragma unroll
    for (int mt = 0; mt < 4; ++mt) {
      const int sbase = wv * 64 + mt * 16;
      const int srow = sbase + (lane & 15);
      const half8 Hf = *(const half8*)(s_hf + srow * HSTRIDE + quad * 8);

      f32x4 acc0 = {dvv[0][0], dvv[0][1], dvv[0][2], dvv[0][3]};
      f32x4 acc1 = {dvv[1][0], dvv[1][1], dvv[1][2], dvv[1][3]};
      acc0 = __builtin_amdgcn_mfma_f32_16x16x32_f16(Whi0, Hf, acc0, 0, 0, 0);
      acc1 = __builtin_amdgcn_mfma_f32_16x16x32_f16(Whi1, Hf, acc1, 0, 0, 0);

      // relu + fp16 pack -> B-frag for layer-2 (k-permutation matches W2f)
      const uint32_t b20 = pk2h(fmaxf(acc0[0], 0.0f), fmaxf(acc0[1], 0.0f));
      const uint32_t b21 = pk2h(fmaxf(acc0[2], 0.0f), fmaxf(acc0[3], 0.0f));
      const uint32_t b22 = pk2h(fmaxf(acc1[0], 0.0f), fmaxf(acc1[1], 0.0f));
      const uint32_t b23 = pk2h(fmaxf(acc1[2], 0.0f), fmaxf(acc1[3], 0.0f));
      const uint4 qq = make_uint4(b20, b21, b22, b23);
      half8 B2; __builtin_memcpy(&B2, &qq, 16);

      f32x4 aC = c2init;
      aC = __builtin_amdgcn_mfma_f32_16x16x32_f16(W2f, B2, aC, 0, 0, 0);

      // quad0 lanes hold rgb rows 0..2 for sample sbase+(lane&15)
      if (quad == 0) {
        const int s = sbase + (lane & 15);
        float4 og;
        og.x = fast_rcp(1.0f + __expf(-aC[0]));
        og.y = fast_rcp(1.0f + __expf(-aC[1]));
        og.z = fast_rcp(1.0f + __expf(-aC[2]));
        og.w = 0.0f;
        *(float4*)(s_rgb + s * RGBS) = og;
      }
    }
  }

  // ---- fine alpha + parallel cumprod over 128 (DPP scan) ----
  const float deltaf = (t < SF - 1) ? (s_zlf[t + 1] - zlf) : 0.0f;
  vf = __expf(-sigf * deltaf);
  float fi = dpp_scan_mul(vf);
  if (lane == 63) s_tot[wv] = fi;
  __syncthreads();   // also makes s_rgb visible
  const float wf = (fast_rcp(vf) - 1.0f) * fi * (wv ? s_tot[0] : 1.0f);

  // ---- outputs ----
  float* o_img = out;
  float* o_w   = out + (size_t)n_rays * 3;
  float* o_z   = out + (size_t)n_rays * (3 + 128);
  float* o_inv = out + (size_t)n_rays * (3 + 256);

  o_w[(size_t)ray * 128 + t] = wf;
  o_z[(size_t)ray * 128 + t] = (zlf + 1.0f) * 0.5f;

  float r0 = wf * s_rgb[t * RGBS + 0];
  float r1 = wf * s_rgb[t * RGBS + 1];
  float r2 = wf * s_rgb[t * RGBS + 2];
  float r3 = wf, r4 = wf * fast_rcp(zf);
  // DPP scan-based reduce: lane 63 holds the wave total
  r0 = dpp_scan_add(r0);
  r1 = dpp_scan_add(r1);
  r2 = dpp_scan_add(r2);
  r3 = dpp_scan_add(r3);
  r4 = dpp_scan_add(r4);
  if (lane == 63) {
    float* p = &s_red[wv * 5];
    p[0] = r0; p[1] = r1; p[2] = r2; p[3] = r3; p[4] = r4;
  }
  __syncthreads();
  if (t == 0) {
    const float accw = s_red[3] + s_red[8];
    const float bgw = 1.0f - accw;
    o_img[(size_t)ray * 3 + 0] = (s_red[0] + s_red[5]) + bgw * bg[0];
    o_img[(size_t)ray * 3 + 1] = (s_red[1] + s_red[6]) + bgw * bg[1];
    o_img[(size_t)ray * 3 + 2] = (s_red[2] + s_red[7]) + bgw * bg[2];
    o_inv[ray] = s_red[4] + s_red[9];
  }
}

extern "C" void kernel_launch(void* const* d_in, const int* in_sizes, int n_in,
                              void* d_out, int out_size, void* d_ws, size_t ws_size,
                              hipStream_t stream) {
  const float* h   = (const float*)d_in[1];
  const float* w   = (const float*)d_in[2];
  const float* K   = (const float*)d_in[3];
  const float* E   = (const float*)d_in[4];
  const float* bg  = (const float*)d_in[5];
  const float* Wd1 = (const float*)d_in[6];
  const float* bd1 = (const float*)d_in[7];
  const float* Wd2 = (const float*)d_in[8];
  const float* bd2 = (const float*)d_in[9];
  const float* Wc1 = (const float*)d_in[10];
  const float* bc1 = (const float*)d_in[11];
  const float* Wc2 = (const float*)d_in[12];
  const float* bc2 = (const float*)d_in[13];
  const int n_rays = in_sizes[1];
  float* wsf = (float*)d_ws;

  if (ws_size >= WS_NEED) {
    pack_weights<<<1, NT, 0, stream>>>(K, Wd1, bd1, Wd2, bd2, Wc1, bc1, Wc2, bc2, wsf);
    nerf_fwd<true><<<n_rays, NT, 0, stream>>>(h, w, K, E, bg, Wd1, bd1, Wd2, bd2,
                                              Wc1, bc1, Wc2, bc2, wsf,
                                              (float*)d_out, n_rays);
  } else {
    nerf_fwd<false><<<n_rays, NT, 0, stream>>>(h, w, K, E, bg, Wd1, bd1, Wd2, bd2,
                                               Wc1, bc1, Wc2, bc2, nullptr,
                                               (float*)d_out, n_rays);
  }
}